// Round 1
// baseline (881.201 us; speedup 1.0000x reference)
//
#include <hip/hip_runtime.h>

#define N_NODES 10000
#define N_EDGES 320000
#define F_IN    3000
#define H1      512
#define H2      64
#define CAP     128   // max in-degree bucket capacity (Poisson mean 32)

// ---------------------------------------------------------------------------
// Bucket edges by destination: per-dst slot via atomic counter.
// ---------------------------------------------------------------------------
__global__ void bucket_build(const int* __restrict__ src, const int* __restrict__ dst,
                             const float* __restrict__ w, int* __restrict__ cnt,
                             int* __restrict__ bsrc, float* __restrict__ bw) {
    int e = blockIdx.x * blockDim.x + threadIdx.x;
    if (e >= N_EDGES) return;
    int d = dst[e];
    int slot = atomicAdd(&cnt[d], 1);
    if (slot < CAP) {
        bsrc[d * CAP + slot] = src[e];
        bw[d * CAP + slot]   = w[e];
    }
}

// ---------------------------------------------------------------------------
// GEMM1: support1 = x @ W1   [10000,3000] @ [3000,512]
// 64x64 tile / block(256), BK=16, each thread 4x4 outputs. fp32 vector ALU.
// ---------------------------------------------------------------------------
__global__ __launch_bounds__(256) void gemm_xw1(const float* __restrict__ A,
                                                const float* __restrict__ B,
                                                float* __restrict__ C) {
    const int M = N_NODES, K = F_IN, Nn = H1;
    __shared__ float As[16][64];  // [k][m] (transposed on load)
    __shared__ float Bs[16][64];  // [k][n]
    const int mBase = blockIdx.x * 64;
    const int nBase = blockIdx.y * 64;
    const int t  = threadIdx.x;
    const int tx = t & 15, ty = t >> 4;

    const int lm  = t >> 2;        // A-load: row in tile (0..63)
    const int lkq = (t & 3) * 4;   // A-load: k quad
    const int lk  = t >> 4;        // B-load: k (0..15)
    const int ln  = (t & 15) * 4;  // B-load: col quad

    float acc[4][4] = {};
    const int arow = mBase + lm;

    for (int k0 = 0; k0 < K; k0 += 16) {
        if (k0 + 16 <= K) {
            float4 a = (arow < M) ? *(const float4*)&A[(size_t)arow * K + k0 + lkq]
                                  : make_float4(0.f, 0.f, 0.f, 0.f);
            As[lkq + 0][lm] = a.x;
            As[lkq + 1][lm] = a.y;
            As[lkq + 2][lm] = a.z;
            As[lkq + 3][lm] = a.w;
            *(float4*)&Bs[lk][ln] = *(const float4*)&B[(size_t)(k0 + lk) * Nn + nBase + ln];
        } else {  // K remainder (3000 = 187*16 + 8)
            #pragma unroll
            for (int j = 0; j < 4; ++j) {
                int kk = k0 + lkq + j;
                As[lkq + j][lm] = (arow < M && kk < K) ? A[(size_t)arow * K + kk] : 0.f;
            }
            int kk = k0 + lk;
            float4 b = (kk < K) ? *(const float4*)&B[(size_t)kk * Nn + nBase + ln]
                                : make_float4(0.f, 0.f, 0.f, 0.f);
            *(float4*)&Bs[lk][ln] = b;
        }
        __syncthreads();
        #pragma unroll
        for (int k = 0; k < 16; ++k) {
            float4 a4 = *(const float4*)&As[k][ty * 4];
            float4 b4 = *(const float4*)&Bs[k][tx * 4];
            float av[4] = {a4.x, a4.y, a4.z, a4.w};
            float bv[4] = {b4.x, b4.y, b4.z, b4.w};
            #pragma unroll
            for (int i = 0; i < 4; ++i)
                #pragma unroll
                for (int j = 0; j < 4; ++j)
                    acc[i][j] += av[i] * bv[j];
        }
        __syncthreads();
    }
    #pragma unroll
    for (int i = 0; i < 4; ++i) {
        int row = mBase + ty * 4 + i;
        if (row < M)
            *(float4*)&C[(size_t)row * Nn + nBase + tx * 4] =
                make_float4(acc[i][0], acc[i][1], acc[i][2], acc[i][3]);
    }
}

// ---------------------------------------------------------------------------
// Gather-formulated segment_sum for h1 (+ReLU): one block per node, 512 cols.
// ---------------------------------------------------------------------------
__global__ __launch_bounds__(256) void gather_h1(const float* __restrict__ sup,
                                                 const int* __restrict__ cnt,
                                                 const int* __restrict__ bsrc,
                                                 const float* __restrict__ bw,
                                                 float* __restrict__ h1) {
    const int n = blockIdx.x;
    const int t = threadIdx.x;
    const int deg = min(cnt[n], CAP);
    float acc0 = 0.f, acc1 = 0.f;
    for (int e = 0; e < deg; ++e) {
        int   s = bsrc[n * CAP + e];
        float w = bw[n * CAP + e];
        const float* row = sup + (size_t)s * H1;
        acc0 += w * row[t];
        acc1 += w * row[t + 256];
    }
    h1[(size_t)n * H1 + t]       = fmaxf(acc0, 0.f);
    h1[(size_t)n * H1 + t + 256] = fmaxf(acc1, 0.f);
}

// ---------------------------------------------------------------------------
// GEMM2+3 fused: sup2[:, 0:64] = h1@W2, sup2[:, 64:128] = h1@W3.
// Block handles 16 rows; h1 rows staged in LDS (32 KB).
// ---------------------------------------------------------------------------
__global__ __launch_bounds__(256) void gemm_h1w23(const float* __restrict__ h1,
                                                  const float* __restrict__ W2,
                                                  const float* __restrict__ W3,
                                                  float* __restrict__ sup2) {
    __shared__ float hs[16][H1];
    const int rBase = blockIdx.x * 16;
    const int t = threadIdx.x;
    for (int idx = t * 4; idx < 16 * H1; idx += 256 * 4) {
        int r = idx >> 9;
        int k = idx & 511;
        *(float4*)&hs[r][k] = *(const float4*)&h1[(size_t)(rBase + r) * H1 + k];
    }
    __syncthreads();
    const int col = t & 127;
    const int rg  = (t >> 7) * 8;
    const float* W = (col < 64) ? (W2 + col) : (W3 + (col - 64));
    float acc[8] = {};
    for (int k = 0; k < H1; ++k) {
        float wv = W[k * 64];
        #pragma unroll
        for (int i = 0; i < 8; ++i) acc[i] += wv * hs[rg + i][k];
    }
    #pragma unroll
    for (int i = 0; i < 8; ++i)
        sup2[(size_t)(rBase + rg + i) * 128 + col] = acc[i];
}

// ---------------------------------------------------------------------------
// Gather for mu / logvar: 2 nodes per block (128 cols each).
// ---------------------------------------------------------------------------
__global__ __launch_bounds__(256) void gather_muvar(const float* __restrict__ sup2,
                                                    const int* __restrict__ cnt,
                                                    const int* __restrict__ bsrc,
                                                    const float* __restrict__ bw,
                                                    float* __restrict__ mu,
                                                    float* __restrict__ lv) {
    const int n = blockIdx.x * 2 + (threadIdx.x >> 7);
    const int c = threadIdx.x & 127;
    const int deg = min(cnt[n], CAP);
    float acc = 0.f;
    for (int e = 0; e < deg; ++e) {
        int   s = bsrc[n * CAP + e];
        float w = bw[n * CAP + e];
        acc += w * sup2[(size_t)s * 128 + c];
    }
    if (c < 64) mu[(size_t)n * 64 + c]        = acc;
    else        lv[(size_t)n * 64 + (c - 64)] = acc;
}

// ---------------------------------------------------------------------------
// pred = mu @ mu.T  [10000,64] x [64,10000]; 64x64 tile / block(256).
// ---------------------------------------------------------------------------
__global__ __launch_bounds__(256) void pred_mm(const float* __restrict__ mu,
                                               float* __restrict__ pred) {
    __shared__ float Ast[64][64];  // [k][m]
    __shared__ float Bst[64][64];  // [k][n]
    const int rb = blockIdx.x * 64, cb = blockIdx.y * 64;
    const int t  = threadIdx.x;
    const int lm = t >> 2, lkq = (t & 3) * 16;
    #pragma unroll
    for (int jj = 0; jj < 4; ++jj) {
        int k  = lkq + jj * 4;
        int ra = rb + lm, rc = cb + lm;
        float4 a = (ra < N_NODES) ? *(const float4*)&mu[(size_t)ra * 64 + k]
                                  : make_float4(0.f, 0.f, 0.f, 0.f);
        float4 b = (rc < N_NODES) ? *(const float4*)&mu[(size_t)rc * 64 + k]
                                  : make_float4(0.f, 0.f, 0.f, 0.f);
        Ast[k + 0][lm] = a.x; Ast[k + 1][lm] = a.y; Ast[k + 2][lm] = a.z; Ast[k + 3][lm] = a.w;
        Bst[k + 0][lm] = b.x; Bst[k + 1][lm] = b.y; Bst[k + 2][lm] = b.z; Bst[k + 3][lm] = b.w;
    }
    __syncthreads();
    const int tx = t & 15, ty = t >> 4;
    float acc[4][4] = {};
    #pragma unroll 8
    for (int k = 0; k < 64; ++k) {
        float4 a4 = *(const float4*)&Ast[k][ty * 4];
        float4 b4 = *(const float4*)&Bst[k][tx * 4];
        float av[4] = {a4.x, a4.y, a4.z, a4.w};
        float bv[4] = {b4.x, b4.y, b4.z, b4.w};
        #pragma unroll
        for (int i = 0; i < 4; ++i)
            #pragma unroll
            for (int j = 0; j < 4; ++j)
                acc[i][j] += av[i] * bv[j];
    }
    const int col = cb + tx * 4;
    #pragma unroll
    for (int i = 0; i < 4; ++i) {
        int row = rb + ty * 4 + i;
        if (row < N_NODES && col < N_NODES)
            *(float4*)&pred[(size_t)row * N_NODES + col] =
                make_float4(acc[i][0], acc[i][1], acc[i][2], acc[i][3]);
    }
}

// ---------------------------------------------------------------------------
extern "C" void kernel_launch(void* const* d_in, const int* in_sizes, int n_in,
                              void* d_out, int out_size, void* d_ws, size_t ws_size,
                              hipStream_t stream) {
    const float* x    = (const float*)d_in[0];
    const int*   esrc = (const int*)d_in[1];
    const int*   edst = (const int*)d_in[2];
    const float* ew   = (const float*)d_in[3];
    const float* W1   = (const float*)d_in[4];
    const float* W2   = (const float*)d_in[5];
    const float* W3   = (const float*)d_in[6];

    float* pred = (float*)d_out;
    float* mu   = pred + (size_t)N_NODES * N_NODES;
    float* lv   = mu   + (size_t)N_NODES * H2;

    char* ws = (char*)d_ws;
    float* support1 = (float*)ws; ws += (size_t)N_NODES * H1 * sizeof(float);
    float* h1       = (float*)ws; ws += (size_t)N_NODES * H1 * sizeof(float);
    float* support2 = (float*)ws; ws += (size_t)N_NODES * 2 * H2 * sizeof(float);
    int*   cnt      = (int*)ws;   ws += (size_t)N_NODES * sizeof(int);
    int*   bsrc     = (int*)ws;   ws += (size_t)N_NODES * CAP * sizeof(int);
    float* bw       = (float*)ws; ws += (size_t)N_NODES * CAP * sizeof(float);

    hipMemsetAsync(cnt, 0, N_NODES * sizeof(int), stream);
    bucket_build<<<(N_EDGES + 255) / 256, 256, 0, stream>>>(esrc, edst, ew, cnt, bsrc, bw);
    gemm_xw1<<<dim3((N_NODES + 63) / 64, H1 / 64), 256, 0, stream>>>(x, W1, support1);
    gather_h1<<<N_NODES, 256, 0, stream>>>(support1, cnt, bsrc, bw, h1);
    gemm_h1w23<<<N_NODES / 16, 256, 0, stream>>>(h1, W2, W3, support2);
    gather_muvar<<<N_NODES / 2, 256, 0, stream>>>(support2, cnt, bsrc, bw, mu, lv);
    pred_mm<<<dim3((N_NODES + 63) / 64, (N_NODES + 63) / 64), 256, 0, stream>>>(mu, pred);
}

// Round 2
// 436.516 us; speedup vs baseline: 2.0187x; 2.0187x over previous
//
#include <hip/hip_runtime.h>
#include <hip/hip_bf16.h>

#define N_NODES 10000
#define N_EDGES 320000
#define F_IN    3000
#define KP      3008   // F_IN padded to multiple of 32 (bf16 MFMA K-step)
#define H1      512
#define H2      64
#define CAP     128    // max in-degree bucket capacity (Poisson mean 32)

typedef float  f32x4  __attribute__((ext_vector_type(4)));
typedef short  bf16x8 __attribute__((ext_vector_type(8)));   // 8 bf16 in 4 VGPRs
typedef unsigned short us8 __attribute__((ext_vector_type(8)));

// fp32 -> bf16 bits, round-to-nearest-even
__device__ __forceinline__ unsigned short f2b(float f) {
    union { float f; unsigned u; } v; v.f = f;
    unsigned r = v.u + 0x7FFF + ((v.u >> 16) & 1);
    return (unsigned short)(r >> 16);
}

// async global->LDS, 16 B per lane; lptr is the WAVE-UNIFORM base (HW adds lane*16)
#define GLOAD_LDS16(gptr, lptr)                                                          \
    __builtin_amdgcn_global_load_lds((const __attribute__((address_space(1))) void*)(gptr), \
                                     (__attribute__((address_space(3))) void*)(lptr),       \
                                     16, 0, 0)

// ---------------------------------------------------------------------------
// Bucket edges by destination: per-dst slot via atomic counter.
// ---------------------------------------------------------------------------
__global__ void bucket_build(const int* __restrict__ src, const int* __restrict__ dst,
                             const float* __restrict__ w, int* __restrict__ cnt,
                             int* __restrict__ bsrc, float* __restrict__ bw) {
    int e = blockIdx.x * blockDim.x + threadIdx.x;
    if (e >= N_EDGES) return;
    int d = dst[e];
    int slot = atomicAdd(&cnt[d], 1);
    if (slot < CAP) {
        bsrc[d * CAP + slot] = src[e];
        bw[d * CAP + slot]   = w[e];
    }
}

// ---------------------------------------------------------------------------
// x [10000][3000] fp32 -> xb [10000][3008] bf16 (zero-padded K tail)
// ---------------------------------------------------------------------------
__global__ __launch_bounds__(256) void convert_x(const float* __restrict__ x,
                                                 unsigned short* __restrict__ xb) {
    int idx = blockIdx.x * 256 + threadIdx.x;      // one thread per 8 outputs
    int r = idx / (KP / 8);
    int g = idx % (KP / 8);
    if (r >= N_NODES) return;
    us8 v;
    if (g * 8 + 8 <= F_IN) {
        float4 a = *(const float4*)&x[(size_t)r * F_IN + g * 8];
        float4 b = *(const float4*)&x[(size_t)r * F_IN + g * 8 + 4];
        v[0] = f2b(a.x); v[1] = f2b(a.y); v[2] = f2b(a.z); v[3] = f2b(a.w);
        v[4] = f2b(b.x); v[5] = f2b(b.y); v[6] = f2b(b.z); v[7] = f2b(b.w);
    } else {
        #pragma unroll
        for (int j = 0; j < 8; ++j) {
            int k = g * 8 + j;
            v[j] = (k < F_IN) ? f2b(x[(size_t)r * F_IN + k]) : (unsigned short)0;
        }
    }
    *(us8*)&xb[(size_t)r * KP + g * 8] = v;
}

// ---------------------------------------------------------------------------
// W1 [3000][512] fp32 -> w1t [512][3008] bf16 (transposed, zero-padded tail)
// ---------------------------------------------------------------------------
__global__ __launch_bounds__(256) void convert_w1(const float* __restrict__ W1,
                                                  unsigned short* __restrict__ w1t) {
    int idx = blockIdx.x * 256 + threadIdx.x;      // 512 cols x 376 k-groups
    int col = idx & 511;
    int g   = idx >> 9;
    if (g >= KP / 8) return;
    us8 v;
    #pragma unroll
    for (int j = 0; j < 8; ++j) {
        int k = g * 8 + j;
        v[j] = (k < F_IN) ? f2b(W1[(size_t)k * H1 + col]) : (unsigned short)0;
    }
    *(us8*)&w1t[(size_t)col * KP + g * 8] = v;
}

// ---------------------------------------------------------------------------
// GEMM1: support1 = x @ W1 via bf16 MFMA.  A = xb [10000][KP] row-major,
// B = w1t [512][KP] (i.e. W1^T) row-major so both fragments are contiguous.
// 128x128 tile, BK=32, 4 waves (each 64x64 = 4x4 frags of 16x16x32).
// ---------------------------------------------------------------------------
__global__ __launch_bounds__(256) void gemm1_mfma(const unsigned short* __restrict__ xb,
                                                  const unsigned short* __restrict__ w1t,
                                                  float* __restrict__ C) {
    __shared__ unsigned short As[128 * 32];   // [row][k] 8 KB
    __shared__ unsigned short Bs[128 * 32];   // [col][k] 8 KB
    const int t = threadIdx.x;
    const int wid = t >> 6, lane = t & 63;
    const int mBase = blockIdx.x * 128;
    const int nBase = blockIdx.y * 128;

    const int wr = (wid >> 1) * 64;    // wave row offset in tile
    const int wc = (wid & 1) * 64;     // wave col offset in tile
    const int fr = lane & 15;          // row/col within 16x16 fragment
    const int fk = (lane >> 4) * 8;    // k base within fragment

    f32x4 acc[4][4] = {};

    for (int k0 = 0; k0 < KP; k0 += 32) {
        #pragma unroll
        for (int j = 0; j < 2; ++j) {
            int o   = j * 4096 + wid * 1024 + lane * 16;  // byte offset in 8 KB tile
            int row = o >> 6;                              // 64 B per row (32 bf16)
            int kb  = o & 63;
            const char* ga = (const char*)xb +
                ((size_t)min(mBase + row, N_NODES - 1) * KP + k0) * 2 + kb;
            GLOAD_LDS16(ga, (char*)As + j * 4096 + wid * 1024);
            const char* gb = (const char*)w1t +
                ((size_t)(nBase + row) * KP + k0) * 2 + kb;
            GLOAD_LDS16(gb, (char*)Bs + j * 4096 + wid * 1024);
        }
        __syncthreads();

        bf16x8 af[4], bfv[4];
        #pragma unroll
        for (int m = 0; m < 4; ++m)
            af[m] = *(const bf16x8*)&As[(wr + m * 16 + fr) * 32 + fk];
        #pragma unroll
        for (int n = 0; n < 4; ++n)
            bfv[n] = *(const bf16x8*)&Bs[(wc + n * 16 + fr) * 32 + fk];
        #pragma unroll
        for (int m = 0; m < 4; ++m)
            #pragma unroll
            for (int n = 0; n < 4; ++n)
                acc[m][n] = __builtin_amdgcn_mfma_f32_16x16x32_bf16(af[m], bfv[n], acc[m][n], 0, 0, 0);
        __syncthreads();
    }

    // C/D layout: col = lane&15, row = (lane>>4)*4 + reg
    #pragma unroll
    for (int m = 0; m < 4; ++m) {
        int rbase = mBase + wr + m * 16 + (lane >> 4) * 4;
        #pragma unroll
        for (int n = 0; n < 4; ++n) {
            int col = nBase + wc + n * 16 + (lane & 15);
            #pragma unroll
            for (int i = 0; i < 4; ++i) {
                int row = rbase + i;
                if (row < N_NODES)
                    C[(size_t)row * H1 + col] = acc[m][n][i];
            }
        }
    }
}

// ---------------------------------------------------------------------------
// Gather-formulated segment_sum for h1 (+ReLU): one block per node, 512 cols.
// ---------------------------------------------------------------------------
__global__ __launch_bounds__(256) void gather_h1(const float* __restrict__ sup,
                                                 const int* __restrict__ cnt,
                                                 const int* __restrict__ bsrc,
                                                 const float* __restrict__ bw,
                                                 float* __restrict__ h1) {
    const int n = blockIdx.x;
    const int t = threadIdx.x;
    const int deg = min(cnt[n], CAP);
    float acc0 = 0.f, acc1 = 0.f;
    for (int e = 0; e < deg; ++e) {
        int   s = bsrc[n * CAP + e];
        float w = bw[n * CAP + e];
        const float* row = sup + (size_t)s * H1;
        acc0 += w * row[t];
        acc1 += w * row[t + 256];
    }
    h1[(size_t)n * H1 + t]       = fmaxf(acc0, 0.f);
    h1[(size_t)n * H1 + t + 256] = fmaxf(acc1, 0.f);
}

// ---------------------------------------------------------------------------
// GEMM2+3 fused: sup2[:, 0:64] = h1@W2, sup2[:, 64:128] = h1@W3.
// ---------------------------------------------------------------------------
__global__ __launch_bounds__(256) void gemm_h1w23(const float* __restrict__ h1,
                                                  const float* __restrict__ W2,
                                                  const float* __restrict__ W3,
                                                  float* __restrict__ sup2) {
    __shared__ float hs[16][H1];
    const int rBase = blockIdx.x * 16;
    const int t = threadIdx.x;
    for (int idx = t * 4; idx < 16 * H1; idx += 256 * 4) {
        int r = idx >> 9;
        int k = idx & 511;
        *(float4*)&hs[r][k] = *(const float4*)&h1[(size_t)(rBase + r) * H1 + k];
    }
    __syncthreads();
    const int col = t & 127;
    const int rg  = (t >> 7) * 8;
    const float* W = (col < 64) ? (W2 + col) : (W3 + (col - 64));
    float acc[8] = {};
    for (int k = 0; k < H1; ++k) {
        float wv = W[k * 64];
        #pragma unroll
        for (int i = 0; i < 8; ++i) acc[i] += wv * hs[rg + i][k];
    }
    #pragma unroll
    for (int i = 0; i < 8; ++i)
        sup2[(size_t)(rBase + rg + i) * 128 + col] = acc[i];
}

// ---------------------------------------------------------------------------
// Gather for mu / logvar; also emits mu as bf16 for the decoder MFMA.
// ---------------------------------------------------------------------------
__global__ __launch_bounds__(256) void gather_muvar(const float* __restrict__ sup2,
                                                    const int* __restrict__ cnt,
                                                    const int* __restrict__ bsrc,
                                                    const float* __restrict__ bw,
                                                    float* __restrict__ mu,
                                                    float* __restrict__ lv,
                                                    unsigned short* __restrict__ mub) {
    const int n = blockIdx.x * 2 + (threadIdx.x >> 7);
    const int c = threadIdx.x & 127;
    const int deg = min(cnt[n], CAP);
    float acc = 0.f;
    for (int e = 0; e < deg; ++e) {
        int   s = bsrc[n * CAP + e];
        float w = bw[n * CAP + e];
        acc += w * sup2[(size_t)s * 128 + c];
    }
    if (c < 64) {
        mu[(size_t)n * 64 + c]  = acc;
        mub[(size_t)n * 64 + c] = f2b(acc);
    } else {
        lv[(size_t)n * 64 + (c - 64)] = acc;
    }
}

// ---------------------------------------------------------------------------
// pred = mu @ mu.T via bf16 MFMA, fragments straight from global (mub is
// 1.28 MB -> L2-resident on every XCD). 128x128 tile / 4 waves, K=64.
// ---------------------------------------------------------------------------
__global__ __launch_bounds__(256) void pred_mfma(const unsigned short* __restrict__ mub,
                                                 float* __restrict__ pred) {
    const int t = threadIdx.x, wid = t >> 6, lane = t & 63;
    const int rb = blockIdx.x * 128 + (wid >> 1) * 64;
    const int cb = blockIdx.y * 128 + (wid & 1) * 64;
    const int fr = lane & 15, fk = (lane >> 4) * 8;
    f32x4 acc[4][4] = {};

    #pragma unroll
    for (int ks = 0; ks < 2; ++ks) {
        bf16x8 af[4], bfv[4];
        #pragma unroll
        for (int m = 0; m < 4; ++m) {
            int r = min(rb + m * 16 + fr, N_NODES - 1);
            af[m] = *(const bf16x8*)&mub[(size_t)r * 64 + ks * 32 + fk];
        }
        #pragma unroll
        for (int n = 0; n < 4; ++n) {
            int c = min(cb + n * 16 + fr, N_NODES - 1);
            bfv[n] = *(const bf16x8*)&mub[(size_t)c * 64 + ks * 32 + fk];
        }
        #pragma unroll
        for (int m = 0; m < 4; ++m)
            #pragma unroll
            for (int n = 0; n < 4; ++n)
                acc[m][n] = __builtin_amdgcn_mfma_f32_16x16x32_bf16(af[m], bfv[n], acc[m][n], 0, 0, 0);
    }

    #pragma unroll
    for (int m = 0; m < 4; ++m) {
        int rbase = rb + m * 16 + (lane >> 4) * 4;
        #pragma unroll
        for (int n = 0; n < 4; ++n) {
            int col = cb + n * 16 + (lane & 15);
            if (col < N_NODES) {
                #pragma unroll
                for (int i = 0; i < 4; ++i) {
                    int row = rbase + i;
                    if (row < N_NODES)
                        pred[(size_t)row * N_NODES + col] = acc[m][n][i];
                }
            }
        }
    }
}

// ---------------------------------------------------------------------------
extern "C" void kernel_launch(void* const* d_in, const int* in_sizes, int n_in,
                              void* d_out, int out_size, void* d_ws, size_t ws_size,
                              hipStream_t stream) {
    const float* x    = (const float*)d_in[0];
    const int*   esrc = (const int*)d_in[1];
    const int*   edst = (const int*)d_in[2];
    const float* ew   = (const float*)d_in[3];
    const float* W1   = (const float*)d_in[4];
    const float* W2   = (const float*)d_in[5];
    const float* W3   = (const float*)d_in[6];

    float* pred = (float*)d_out;
    float* mu   = pred + (size_t)N_NODES * N_NODES;
    float* lv   = mu   + (size_t)N_NODES * H2;

    char* ws = (char*)d_ws;
    float* support1 = (float*)ws; ws += (size_t)N_NODES * H1 * sizeof(float);
    float* h1       = (float*)ws; ws += (size_t)N_NODES * H1 * sizeof(float);
    float* support2 = (float*)ws; ws += (size_t)N_NODES * 2 * H2 * sizeof(float);
    int*   cnt      = (int*)ws;   ws += (size_t)N_NODES * sizeof(int);
    int*   bsrc     = (int*)ws;   ws += (size_t)N_NODES * CAP * sizeof(int);
    float* bw       = (float*)ws; ws += (size_t)N_NODES * CAP * sizeof(float);
    unsigned short* xb  = (unsigned short*)ws; ws += (size_t)N_NODES * KP * sizeof(short);
    unsigned short* w1t = (unsigned short*)ws; ws += (size_t)H1 * KP * sizeof(short);
    unsigned short* mub = (unsigned short*)ws; ws += (size_t)N_NODES * H2 * sizeof(short);

    hipMemsetAsync(cnt, 0, N_NODES * sizeof(int), stream);
    bucket_build<<<(N_EDGES + 255) / 256, 256, 0, stream>>>(esrc, edst, ew, cnt, bsrc, bw);
    convert_x<<<(N_NODES * (KP / 8) + 255) / 256, 256, 0, stream>>>(x, xb);
    convert_w1<<<(H1 * (KP / 8) + 255) / 256, 256, 0, stream>>>(W1, w1t);
    gemm1_mfma<<<dim3((N_NODES + 127) / 128, H1 / 128), 256, 0, stream>>>(xb, w1t, support1);
    gather_h1<<<N_NODES, 256, 0, stream>>>(support1, cnt, bsrc, bw, h1);
    gemm_h1w23<<<N_NODES / 16, 256, 0, stream>>>(h1, W2, W3, support2);
    gather_muvar<<<N_NODES / 2, 256, 0, stream>>>(support2, cnt, bsrc, bw, mu, lv, mub);
    pred_mfma<<<dim3((N_NODES + 127) / 128, (N_NODES + 127) / 128), 256, 0, stream>>>(mub, pred);
}

// Round 3
// 383.097 us; speedup vs baseline: 2.3002x; 1.1394x over previous
//
#include <hip/hip_runtime.h>
#include <hip/hip_bf16.h>

#define N_NODES 10000
#define N_EDGES 320000
#define F_IN    3000
#define KP      3008   // F_IN padded to multiple of 32 (bf16 MFMA K-step)
#define H1      512
#define H2      64
#define CAP     128    // max in-degree bucket capacity (Poisson mean 32)

typedef float  f32x4  __attribute__((ext_vector_type(4)));
typedef short  bf16x8 __attribute__((ext_vector_type(8)));
typedef unsigned short us8 __attribute__((ext_vector_type(8)));

// fp32 -> bf16 bits, round-to-nearest-even
__device__ __forceinline__ unsigned short f2b(float f) {
    union { float f; unsigned u; } v; v.f = f;
    unsigned r = v.u + 0x7FFF + ((v.u >> 16) & 1);
    return (unsigned short)(r >> 16);
}
__device__ __forceinline__ float b2f(unsigned short b) {
    union { unsigned u; float f; } v; v.u = ((unsigned)b) << 16;
    return v.f;
}

// async global->LDS, 16 B per lane; LDS base is WAVE-UNIFORM (HW adds lane*16)
#define GLOAD_LDS16(gptr, lptr)                                                             \
    __builtin_amdgcn_global_load_lds((const __attribute__((address_space(1))) void*)(gptr), \
                                     (__attribute__((address_space(3))) void*)(lptr),       \
                                     16, 0, 0)

// ---------------------------------------------------------------------------
// Merged prep: [0,1250) bucket_build | [1250,15938) convert_x | [15938,16314) convert_w1
// ---------------------------------------------------------------------------
#define NB_BUCKET 1250
#define NB_CONVX  14688   // ceil(10000*376/256)
#define NB_CONVW  376     // 47 k-tiles x 8 col-tiles

__global__ __launch_bounds__(256) void prep(const int* __restrict__ src,
                                            const int* __restrict__ dst,
                                            const float* __restrict__ w,
                                            const float* __restrict__ x,
                                            const float* __restrict__ W1,
                                            int* __restrict__ cnt,
                                            int* __restrict__ bsrc,
                                            float* __restrict__ bw,
                                            unsigned short* __restrict__ xb,
                                            unsigned short* __restrict__ w1t) {
    __shared__ float tr[64][65];
    const int b = blockIdx.x;
    const int t = threadIdx.x;
    if (b < NB_BUCKET) {
        int e = b * 256 + t;
        if (e >= N_EDGES) return;
        int d = dst[e];
        int slot = atomicAdd(&cnt[d], 1);
        if (slot < CAP) {
            bsrc[d * CAP + slot] = src[e];
            bw[d * CAP + slot]   = w[e];
        }
    } else if (b < NB_BUCKET + NB_CONVX) {
        int idx = (b - NB_BUCKET) * 256 + t;   // one thread per 8 bf16 outputs
        int r = idx / (KP / 8);
        int g = idx % (KP / 8);
        if (r >= N_NODES) return;
        us8 v;
        if (g * 8 + 8 <= F_IN) {
            float4 a = *(const float4*)&x[(size_t)r * F_IN + g * 8];
            float4 c = *(const float4*)&x[(size_t)r * F_IN + g * 8 + 4];
            v[0] = f2b(a.x); v[1] = f2b(a.y); v[2] = f2b(a.z); v[3] = f2b(a.w);
            v[4] = f2b(c.x); v[5] = f2b(c.y); v[6] = f2b(c.z); v[7] = f2b(c.w);
        } else {
            #pragma unroll
            for (int j = 0; j < 8; ++j) {
                int k = g * 8 + j;
                v[j] = (k < F_IN) ? f2b(x[(size_t)r * F_IN + k]) : (unsigned short)0;
            }
        }
        *(us8*)&xb[(size_t)r * KP + g * 8] = v;
    } else {
        // W1 [3000][512] fp32 -> w1t [512][3008] bf16, LDS-transposed tiles
        int bb = b - NB_BUCKET - NB_CONVX;
        int kBase = (bb >> 3) * 64;
        int cBase = (bb & 7) * 64;
        int col = cBase + (t & 63);
        #pragma unroll
        for (int i = 0; i < 16; ++i) {
            int row = kBase + i * 4 + (t >> 6);
            float v = (row < F_IN) ? W1[(size_t)row * H1 + col] : 0.f;
            tr[t & 63][i * 4 + (t >> 6)] = v;
        }
        __syncthreads();
        int c = t >> 2, kq = (t & 3) * 16;
        us8 o0, o1;
        #pragma unroll
        for (int j = 0; j < 8; ++j) { o0[j] = f2b(tr[c][kq + j]); o1[j] = f2b(tr[c][kq + 8 + j]); }
        *(us8*)&w1t[(size_t)(cBase + c) * KP + kBase + kq]     = o0;
        *(us8*)&w1t[(size_t)(cBase + c) * KP + kBase + kq + 8] = o1;
    }
}

// ---------------------------------------------------------------------------
// GEMM1: support1b(bf16) = x @ W1 via bf16 MFMA. A = xb [10000][KP],
// B = w1t [512][KP] (=W1^T). Tile 128x64, BK=32, 4 waves (each 64x32).
// 632 blocks -> >=2 blocks/CU (fixes round-2 occupancy tail).
// ---------------------------------------------------------------------------
__global__ __launch_bounds__(256) void gemm1_mfma(const unsigned short* __restrict__ xb,
                                                  const unsigned short* __restrict__ w1t,
                                                  unsigned short* __restrict__ Cb) {
    __shared__ unsigned short As[128 * 32];   // [row][k] 8 KB
    __shared__ unsigned short Bs[64 * 32];    // [col][k] 4 KB
    const int t = threadIdx.x;
    const int wid = t >> 6, lane = t & 63;
    const int mBase = blockIdx.x * 128;
    const int nBase = blockIdx.y * 64;

    const int wr = (wid >> 1) * 64;    // wave row offset
    const int wc = (wid & 1) * 32;     // wave col offset
    const int fr = lane & 15;
    const int fk = (lane >> 4) * 8;

    // staging addresses: A chunks {wid, wid+4} of 8, B chunk {wid} of 4.
    // chunk c = 16 rows x 32 bf16; lane covers row c*16+lane/4, kq=(lane&3)*8
    const int arow0 = min(mBase + wid * 16 + (lane >> 2), N_NODES - 1);
    const int arow1 = min(mBase + (wid + 4) * 16 + (lane >> 2), N_NODES - 1);
    const int brow  = nBase + wid * 16 + (lane >> 2);
    const int kq    = (lane & 3) * 8;

    f32x4 acc[4][2] = {};

    for (int k0 = 0; k0 < KP; k0 += 32) {
        GLOAD_LDS16(&xb[(size_t)arow0 * KP + k0 + kq], &As[wid * 512]);
        GLOAD_LDS16(&xb[(size_t)arow1 * KP + k0 + kq], &As[(wid + 4) * 512]);
        GLOAD_LDS16(&w1t[(size_t)brow * KP + k0 + kq], &Bs[wid * 512]);
        __syncthreads();

        bf16x8 af[4], bfv[2];
        #pragma unroll
        for (int m = 0; m < 4; ++m)
            af[m] = *(const bf16x8*)&As[(wr + m * 16 + fr) * 32 + fk];
        #pragma unroll
        for (int n = 0; n < 2; ++n)
            bfv[n] = *(const bf16x8*)&Bs[(wc + n * 16 + fr) * 32 + fk];
        #pragma unroll
        for (int m = 0; m < 4; ++m)
            #pragma unroll
            for (int n = 0; n < 2; ++n)
                acc[m][n] = __builtin_amdgcn_mfma_f32_16x16x32_bf16(af[m], bfv[n], acc[m][n], 0, 0, 0);
        __syncthreads();
    }

    // C/D layout: col = lane&15, row = (lane>>4)*4 + reg
    #pragma unroll
    for (int m = 0; m < 4; ++m) {
        int rbase = mBase + wr + m * 16 + (lane >> 4) * 4;
        #pragma unroll
        for (int n = 0; n < 2; ++n) {
            int col = nBase + wc + n * 16 + (lane & 15);
            #pragma unroll
            for (int i = 0; i < 4; ++i) {
                int row = rbase + i;
                if (row < N_NODES)
                    Cb[(size_t)row * H1 + col] = f2b(acc[m][n][i]);
            }
        }
    }
}

// ---------------------------------------------------------------------------
// gather h1 (+ReLU): one WAVE per node; lane holds 8 cols (bf16x8 = 16B/lane).
// support1b is 10 MB -> L3-resident; accumulate fp32.
// ---------------------------------------------------------------------------
__global__ __launch_bounds__(256) void gather_h1(const unsigned short* __restrict__ sup,
                                                 const int* __restrict__ cnt,
                                                 const int* __restrict__ bsrc,
                                                 const float* __restrict__ bw,
                                                 float* __restrict__ h1) {
    const int wid  = threadIdx.x >> 6;
    const int lane = threadIdx.x & 63;
    const int n    = blockIdx.x * 4 + wid;
    const int deg  = min(cnt[n], CAP);
    float acc[8] = {};
    for (int e = 0; e < deg; ++e) {
        int   s = bsrc[n * CAP + e];
        float w = bw[n * CAP + e];
        us8 v = *(const us8*)&sup[(size_t)s * H1 + lane * 8];
        #pragma unroll
        for (int j = 0; j < 8; ++j) acc[j] += w * b2f(v[j]);
    }
    float4 o0 = make_float4(fmaxf(acc[0], 0.f), fmaxf(acc[1], 0.f), fmaxf(acc[2], 0.f), fmaxf(acc[3], 0.f));
    float4 o1 = make_float4(fmaxf(acc[4], 0.f), fmaxf(acc[5], 0.f), fmaxf(acc[6], 0.f), fmaxf(acc[7], 0.f));
    *(float4*)&h1[(size_t)n * H1 + lane * 8]     = o0;
    *(float4*)&h1[(size_t)n * H1 + lane * 8 + 4] = o1;
}

// ---------------------------------------------------------------------------
// GEMM2+3 fused: sup2[:, 0:64] = h1@W2, sup2[:, 64:128] = h1@W3. fp32 vector.
// ---------------------------------------------------------------------------
__global__ __launch_bounds__(256) void gemm_h1w23(const float* __restrict__ h1,
                                                  const float* __restrict__ W2,
                                                  const float* __restrict__ W3,
                                                  float* __restrict__ sup2) {
    __shared__ float hs[16][H1];
    const int rBase = blockIdx.x * 16;
    const int t = threadIdx.x;
    for (int idx = t * 4; idx < 16 * H1; idx += 256 * 4) {
        int r = idx >> 9;
        int k = idx & 511;
        *(float4*)&hs[r][k] = *(const float4*)&h1[(size_t)(rBase + r) * H1 + k];
    }
    __syncthreads();
    const int col = t & 127;
    const int rg  = (t >> 7) * 8;
    const float* W = (col < 64) ? (W2 + col) : (W3 + (col - 64));
    float acc[8] = {};
    for (int k = 0; k < H1; ++k) {
        float wv = W[k * 64];
        #pragma unroll
        for (int i = 0; i < 8; ++i) acc[i] += wv * hs[rg + i][k];
    }
    #pragma unroll
    for (int i = 0; i < 8; ++i)
        sup2[(size_t)(rBase + rg + i) * 128 + col] = acc[i];
}

// ---------------------------------------------------------------------------
// Gather mu/logvar: 8 nodes/block, 32 lanes x float4 per node.
// ---------------------------------------------------------------------------
__global__ __launch_bounds__(256) void gather_muvar(const float* __restrict__ sup2,
                                                    const int* __restrict__ cnt,
                                                    const int* __restrict__ bsrc,
                                                    const float* __restrict__ bw,
                                                    float* __restrict__ mu,
                                                    float* __restrict__ lv,
                                                    unsigned short* __restrict__ mub) {
    const int n  = blockIdx.x * 8 + (threadIdx.x >> 5);
    const int c4 = (threadIdx.x & 31) * 4;
    const int deg = min(cnt[n], CAP);
    float4 acc = make_float4(0.f, 0.f, 0.f, 0.f);
    for (int e = 0; e < deg; ++e) {
        int   s = bsrc[n * CAP + e];
        float w = bw[n * CAP + e];
        float4 v = *(const float4*)&sup2[(size_t)s * 128 + c4];
        acc.x += w * v.x; acc.y += w * v.y; acc.z += w * v.z; acc.w += w * v.w;
    }
    if (c4 < 64) {
        *(float4*)&mu[(size_t)n * 64 + c4] = acc;
        mub[(size_t)n * 64 + c4 + 0] = f2b(acc.x);
        mub[(size_t)n * 64 + c4 + 1] = f2b(acc.y);
        mub[(size_t)n * 64 + c4 + 2] = f2b(acc.z);
        mub[(size_t)n * 64 + c4 + 3] = f2b(acc.w);
    } else {
        *(float4*)&lv[(size_t)n * 64 + (c4 - 64)] = acc;
    }
}

// ---------------------------------------------------------------------------
// pred = mu @ mu.T via bf16 MFMA; mub (1.28 MB) is L2-resident.
// Epilogue stages through LDS -> fully-coalesced dwordx4 stores (256B rows).
// ---------------------------------------------------------------------------
__global__ __launch_bounds__(256) void pred_mfma(const unsigned short* __restrict__ mub,
                                                 float* __restrict__ pred) {
    __shared__ float st[4][16][68];
    const int t = threadIdx.x, wid = t >> 6, lane = t & 63;
    const int rb = blockIdx.x * 128 + (wid >> 1) * 64;
    const int cb = blockIdx.y * 128 + (wid & 1) * 64;
    const int fr = lane & 15, fk = (lane >> 4) * 8;
    f32x4 acc[4][4] = {};

    #pragma unroll
    for (int ks = 0; ks < 2; ++ks) {
        bf16x8 af[4], bfv[4];
        #pragma unroll
        for (int m = 0; m < 4; ++m) {
            int r = min(rb + m * 16 + fr, N_NODES - 1);
            af[m] = *(const bf16x8*)&mub[(size_t)r * 64 + ks * 32 + fk];
        }
        #pragma unroll
        for (int n = 0; n < 4; ++n) {
            int c = min(cb + n * 16 + fr, N_NODES - 1);
            bfv[n] = *(const bf16x8*)&mub[(size_t)c * 64 + ks * 32 + fk];
        }
        #pragma unroll
        for (int m = 0; m < 4; ++m)
            #pragma unroll
            for (int n = 0; n < 4; ++n)
                acc[m][n] = __builtin_amdgcn_mfma_f32_16x16x32_bf16(af[m], bfv[n], acc[m][n], 0, 0, 0);
    }

    // stage each 16x64 row-group in LDS, emit coalesced float4 stores
    #pragma unroll
    for (int m = 0; m < 4; ++m) {
        #pragma unroll
        for (int n = 0; n < 4; ++n)
            #pragma unroll
            for (int i = 0; i < 4; ++i)
                st[wid][(lane >> 4) * 4 + i][n * 16 + (lane & 15)] = acc[m][n][i];
        // wave-private region: in-wave lgkmcnt ordering suffices (no barrier)
        int rbase = rb + m * 16;
        #pragma unroll
        for (int it = 0; it < 4; ++it) {
            int row   = it * 4 + (lane >> 4);
            int chunk = lane & 15;
            int grow  = rbase + row;
            int gcol  = cb + chunk * 4;
            if (grow < N_NODES) {
                float4 v = *(const float4*)&st[wid][row][chunk * 4];
                if (gcol + 3 < N_NODES) {
                    *(float4*)&pred[(size_t)grow * N_NODES + gcol] = v;
                } else {
                    float vv[4] = {v.x, v.y, v.z, v.w};
                    #pragma unroll
                    for (int j = 0; j < 4; ++j)
                        if (gcol + j < N_NODES) pred[(size_t)grow * N_NODES + gcol + j] = vv[j];
                }
            }
        }
    }
}

// ---------------------------------------------------------------------------
extern "C" void kernel_launch(void* const* d_in, const int* in_sizes, int n_in,
                              void* d_out, int out_size, void* d_ws, size_t ws_size,
                              hipStream_t stream) {
    const float* x    = (const float*)d_in[0];
    const int*   esrc = (const int*)d_in[1];
    const int*   edst = (const int*)d_in[2];
    const float* ew   = (const float*)d_in[3];
    const float* W1   = (const float*)d_in[4];
    const float* W2   = (const float*)d_in[5];
    const float* W3   = (const float*)d_in[6];

    float* pred = (float*)d_out;
    float* mu   = pred + (size_t)N_NODES * N_NODES;
    float* lv   = mu   + (size_t)N_NODES * H2;

    char* ws = (char*)d_ws;
    unsigned short* sup1b = (unsigned short*)ws; ws += (size_t)N_NODES * H1 * sizeof(short);
    float* h1       = (float*)ws; ws += (size_t)N_NODES * H1 * sizeof(float);
    float* support2 = (float*)ws; ws += (size_t)N_NODES * 2 * H2 * sizeof(float);
    int*   cnt      = (int*)ws;   ws += (size_t)N_NODES * sizeof(int);
    int*   bsrc     = (int*)ws;   ws += (size_t)N_NODES * CAP * sizeof(int);
    float* bw       = (float*)ws; ws += (size_t)N_NODES * CAP * sizeof(float);
    unsigned short* xb  = (unsigned short*)ws; ws += (size_t)N_NODES * KP * sizeof(short);
    unsigned short* w1t = (unsigned short*)ws; ws += (size_t)H1 * KP * sizeof(short);
    unsigned short* mub = (unsigned short*)ws; ws += (size_t)N_NODES * H2 * sizeof(short);

    hipMemsetAsync(cnt, 0, N_NODES * sizeof(int), stream);
    prep<<<NB_BUCKET + NB_CONVX + NB_CONVW, 256, 0, stream>>>(esrc, edst, ew, x, W1,
                                                              cnt, bsrc, bw, xb, w1t);
    gemm1_mfma<<<dim3((N_NODES + 127) / 128, H1 / 64), 256, 0, stream>>>(xb, w1t, sup1b);
    gather_h1<<<N_NODES / 4, 256, 0, stream>>>(sup1b, cnt, bsrc, bw, h1);
    gemm_h1w23<<<N_NODES / 16, 256, 0, stream>>>(h1, W2, W3, support2);
    gather_muvar<<<N_NODES / 8, 256, 0, stream>>>(support2, cnt, bsrc, bw, mu, lv, mub);
    pred_mfma<<<dim3((N_NODES + 127) / 128, (N_NODES + 127) / 128), 256, 0, stream>>>(mub, pred);
}

// Round 5
// 344.459 us; speedup vs baseline: 2.5582x; 1.1122x over previous
//
#include <hip/hip_runtime.h>
#include <hip/hip_bf16.h>

#define N_NODES 10000
#define N_EDGES 320000
#define F_IN    3000
#define KP      3008   // F_IN padded to multiple of 32 (bf16 MFMA K-step)
#define H1      512
#define H2      64
#define CAP     128    // max in-degree bucket capacity (Poisson mean 32)
#define NT      (KP / 32)   // 94 K-tiles in gemm1

typedef float  f32x4  __attribute__((ext_vector_type(4)));
typedef short  bf16x8 __attribute__((ext_vector_type(8)));
typedef unsigned short us8 __attribute__((ext_vector_type(8)));

// fp32 -> bf16 bits, round-to-nearest-even
__device__ __forceinline__ unsigned short f2b(float f) {
    union { float f; unsigned u; } v; v.f = f;
    unsigned r = v.u + 0x7FFF + ((v.u >> 16) & 1);
    return (unsigned short)(r >> 16);
}
__device__ __forceinline__ float b2f(unsigned short b) {
    union { unsigned u; float f; } v; v.u = ((unsigned)b) << 16;
    return v.f;
}

// async global->LDS, 16 B per lane; LDS base is WAVE-UNIFORM (HW adds lane*16)
#define GLOAD_LDS16(gptr, lptr)                                                             \
    __builtin_amdgcn_global_load_lds((const __attribute__((address_space(1))) void*)(gptr), \
                                     (__attribute__((address_space(3))) void*)(lptr),       \
                                     16, 0, 0)

// ---------------------------------------------------------------------------
// Merged prep: [0,1250) bucket_build | [1250,15938) convert_x | [15938,16314) convert_w1
// ---------------------------------------------------------------------------
#define NB_BUCKET 1250
#define NB_CONVX  14688   // ceil(10000*376/256)
#define NB_CONVW  376     // 47 k-tiles x 8 col-tiles

__global__ __launch_bounds__(256) void prep(const int* __restrict__ src,
                                            const int* __restrict__ dst,
                                            const float* __restrict__ w,
                                            const float* __restrict__ x,
                                            const float* __restrict__ W1,
                                            int* __restrict__ cnt,
                                            int* __restrict__ bsrc,
                                            float* __restrict__ bw,
                                            unsigned short* __restrict__ xb,
                                            unsigned short* __restrict__ w1t) {
    __shared__ float tr[64][65];
    const int b = blockIdx.x;
    const int t = threadIdx.x;
    if (b < NB_BUCKET) {
        int e = b * 256 + t;
        if (e >= N_EDGES) return;
        int d = dst[e];
        int slot = atomicAdd(&cnt[d], 1);
        if (slot < CAP) {
            bsrc[d * CAP + slot] = src[e];
            bw[d * CAP + slot]   = w[e];
        }
    } else if (b < NB_BUCKET + NB_CONVX) {
        int idx = (b - NB_BUCKET) * 256 + t;   // one thread per 8 bf16 outputs
        int r = idx / (KP / 8);
        int g = idx % (KP / 8);
        if (r >= N_NODES) return;
        us8 v;
        if (g * 8 + 8 <= F_IN) {
            float4 a = *(const float4*)&x[(size_t)r * F_IN + g * 8];
            float4 c = *(const float4*)&x[(size_t)r * F_IN + g * 8 + 4];
            v[0] = f2b(a.x); v[1] = f2b(a.y); v[2] = f2b(a.z); v[3] = f2b(a.w);
            v[4] = f2b(c.x); v[5] = f2b(c.y); v[6] = f2b(c.z); v[7] = f2b(c.w);
        } else {
            #pragma unroll
            for (int j = 0; j < 8; ++j) {
                int k = g * 8 + j;
                v[j] = (k < F_IN) ? f2b(x[(size_t)r * F_IN + k]) : (unsigned short)0;
            }
        }
        *(us8*)&xb[(size_t)r * KP + g * 8] = v;
    } else {
        // W1 [3000][512] fp32 -> w1t [512][3008] bf16, LDS-transposed tiles
        int bb = b - NB_BUCKET - NB_CONVX;
        int kBase = (bb >> 3) * 64;
        int cBase = (bb & 7) * 64;
        int col = cBase + (t & 63);
        #pragma unroll
        for (int i = 0; i < 16; ++i) {
            int row = kBase + i * 4 + (t >> 6);
            float v = (row < F_IN) ? W1[(size_t)row * H1 + col] : 0.f;
            tr[t & 63][i * 4 + (t >> 6)] = v;
        }
        __syncthreads();
        int c = t >> 2, kq = (t & 3) * 16;
        us8 o0, o1;
        #pragma unroll
        for (int j = 0; j < 8; ++j) { o0[j] = f2b(tr[c][kq + j]); o1[j] = f2b(tr[c][kq + 8 + j]); }
        *(us8*)&w1t[(size_t)(cBase + c) * KP + kBase + kq]     = o0;
        *(us8*)&w1t[(size_t)(cBase + c) * KP + kBase + kq + 8] = o1;
    }
}

// ---------------------------------------------------------------------------
// GEMM1: support1b(bf16) = x @ W1. A = xb [10000][KP], B = w1t [512][KP].
// Tile 128x64, BK=32, 4 waves. Double-buffered LDS, 2-phase pipeline
// (stage next tile BEFORE computing current; one drain/barrier per K-step).
// Grid: 640 flat blocks, XCD-swizzled so the 8 N-panels sharing an A-tile
// run consecutively on one XCD (A fetched once/XCD; w1t 3MB L2-resident).
// ---------------------------------------------------------------------------
__global__ __launch_bounds__(256) void gemm1_mfma(const unsigned short* __restrict__ xb,
                                                  const unsigned short* __restrict__ w1t,
                                                  unsigned short* __restrict__ Cb) {
    __shared__ unsigned short As[2][128 * 32];   // 2 x 8 KB
    __shared__ unsigned short Bs[2][64 * 32];    // 2 x 4 KB
    // XCD swizzle: xcd k owns x in [k*10,(k+1)*10), all 8 y each, y fastest.
    const int f  = blockIdx.x;          // 640 = 8 xcd * 80
    const int k8 = f & 7;               // xcd (dispatch round-robins f%8)
    const int j  = f >> 3;              // 0..79 within xcd
    const int bx = k8 * 10 + (j >> 3);  // 0..79 (bx=79 is padding: stores skipped)
    const int by = j & 7;
    const int mBase = bx * 128;
    const int nBase = by * 64;

    const int t = threadIdx.x;
    const int wid = t >> 6, lane = t & 63;
    const int wr = (wid >> 1) * 64;
    const int wc = (wid & 1) * 32;
    const int fr = lane & 15;
    const int fk = (lane >> 4) * 8;

    const int arow0 = min(mBase + wid * 16 + (lane >> 2), N_NODES - 1);
    const int arow1 = min(mBase + (wid + 4) * 16 + (lane >> 2), N_NODES - 1);
    const int brow  = nBase + wid * 16 + (lane >> 2);
    const int kq    = (lane & 3) * 8;

    f32x4 acc[4][2] = {};

#define STAGE1(c, k0)                                                          \
    do {                                                                       \
        GLOAD_LDS16(&xb[(size_t)arow0 * KP + (k0) + kq], &As[c][wid * 512]);   \
        GLOAD_LDS16(&xb[(size_t)arow1 * KP + (k0) + kq], &As[c][(wid + 4) * 512]); \
        GLOAD_LDS16(&w1t[(size_t)brow * KP + (k0) + kq], &Bs[c][wid * 512]);   \
    } while (0)

#define COMPUTE1(c)                                                            \
    do {                                                                       \
        bf16x8 af[4], bfv[2];                                                  \
        _Pragma("unroll")                                                      \
        for (int m = 0; m < 4; ++m)                                            \
            af[m] = *(const bf16x8*)&As[c][(wr + m * 16 + fr) * 32 + fk];      \
        _Pragma("unroll")                                                      \
        for (int n = 0; n < 2; ++n)                                            \
            bfv[n] = *(const bf16x8*)&Bs[c][(wc + n * 16 + fr) * 32 + fk];     \
        _Pragma("unroll")                                                      \
        for (int m = 0; m < 4; ++m)                                            \
            _Pragma("unroll")                                                  \
            for (int n = 0; n < 2; ++n)                                        \
                acc[m][n] = __builtin_amdgcn_mfma_f32_16x16x32_bf16(af[m], bfv[n], acc[m][n], 0, 0, 0); \
    } while (0)

    STAGE1(0, 0);
    __syncthreads();                 // drain prologue stage
    int cur = 0;
    for (int tt = 0; tt < NT - 1; ++tt) {
        STAGE1(cur ^ 1, (tt + 1) * 32);   // next tile in flight over compute
        COMPUTE1(cur);
        __syncthreads();                  // drains vmcnt+lgkm; buffers swap-safe
        cur ^= 1;
    }
    COMPUTE1(cur);

#undef STAGE1
#undef COMPUTE1

    // C/D layout: col = lane&15, row = (lane>>4)*4 + reg
    #pragma unroll
    for (int m = 0; m < 4; ++m) {
        int rbase = mBase + wr + m * 16 + (lane >> 4) * 4;
        #pragma unroll
        for (int n = 0; n < 2; ++n) {
            int col = nBase + wc + n * 16 + (lane & 15);
            #pragma unroll
            for (int i = 0; i < 4; ++i) {
                int row = rbase + i;
                if (row < N_NODES)
                    Cb[(size_t)row * H1 + col] = f2b(acc[m][n][i]);
            }
        }
    }
}

// ---------------------------------------------------------------------------
// gather h1 (+ReLU): one WAVE per node; lane holds 8 cols (bf16x8 = 16B/lane).
// ---------------------------------------------------------------------------
__global__ __launch_bounds__(256) void gather_h1(const unsigned short* __restrict__ sup,
                                                 const int* __restrict__ cnt,
                                                 const int* __restrict__ bsrc,
                                                 const float* __restrict__ bw,
                                                 float* __restrict__ h1) {
    const int wid  = threadIdx.x >> 6;
    const int lane = threadIdx.x & 63;
    const int n    = blockIdx.x * 4 + wid;
    const int deg  = min(cnt[n], CAP);
    float acc[8] = {};
    for (int e = 0; e < deg; ++e) {
        int   s = bsrc[n * CAP + e];
        float w = bw[n * CAP + e];
        us8 v = *(const us8*)&sup[(size_t)s * H1 + lane * 8];
        #pragma unroll
        for (int j = 0; j < 8; ++j) acc[j] += w * b2f(v[j]);
    }
    float4 o0 = make_float4(fmaxf(acc[0], 0.f), fmaxf(acc[1], 0.f), fmaxf(acc[2], 0.f), fmaxf(acc[3], 0.f));
    float4 o1 = make_float4(fmaxf(acc[4], 0.f), fmaxf(acc[5], 0.f), fmaxf(acc[6], 0.f), fmaxf(acc[7], 0.f));
    *(float4*)&h1[(size_t)n * H1 + lane * 8]     = o0;
    *(float4*)&h1[(size_t)n * H1 + lane * 8 + 4] = o1;
}

// ---------------------------------------------------------------------------
// GEMM2+3 fused: sup2[:, 0:64] = h1@W2, sup2[:, 64:128] = h1@W3. fp32 vector.
// ---------------------------------------------------------------------------
__global__ __launch_bounds__(256) void gemm_h1w23(const float* __restrict__ h1,
                                                  const float* __restrict__ W2,
                                                  const float* __restrict__ W3,
                                                  float* __restrict__ sup2) {
    __shared__ float hs[16][H1];
    const int rBase = blockIdx.x * 16;
    const int t = threadIdx.x;
    for (int idx = t * 4; idx < 16 * H1; idx += 256 * 4) {
        int r = idx >> 9;
        int k = idx & 511;
        *(float4*)&hs[r][k] = *(const float4*)&h1[(size_t)(rBase + r) * H1 + k];
    }
    __syncthreads();
    const int col = t & 127;
    const int rg  = (t >> 7) * 8;
    const float* W = (col < 64) ? (W2 + col) : (W3 + (col - 64));
    float acc[8] = {};
    for (int k = 0; k < H1; ++k) {
        float wv = W[k * 64];
        #pragma unroll
        for (int i = 0; i < 8; ++i) acc[i] += wv * hs[rg + i][k];
    }
    #pragma unroll
    for (int i = 0; i < 8; ++i)
        sup2[(size_t)(rBase + rg + i) * 128 + col] = acc[i];
}

// ---------------------------------------------------------------------------
// Gather mu/logvar: 8 nodes/block, 32 lanes x float4 per node.
// ---------------------------------------------------------------------------
__global__ __launch_bounds__(256) void gather_muvar(const float* __restrict__ sup2,
                                                    const int* __restrict__ cnt,
                                                    const int* __restrict__ bsrc,
                                                    const float* __restrict__ bw,
                                                    float* __restrict__ mu,
                                                    float* __restrict__ lv,
                                                    unsigned short* __restrict__ mub) {
    const int n  = blockIdx.x * 8 + (threadIdx.x >> 5);
    const int c4 = (threadIdx.x & 31) * 4;
    const int deg = min(cnt[n], CAP);
    float4 acc = make_float4(0.f, 0.f, 0.f, 0.f);
    for (int e = 0; e < deg; ++e) {
        int   s = bsrc[n * CAP + e];
        float w = bw[n * CAP + e];
        float4 v = *(const float4*)&sup2[(size_t)s * 128 + c4];
        acc.x += w * v.x; acc.y += w * v.y; acc.z += w * v.z; acc.w += w * v.w;
    }
    if (c4 < 64) {
        *(float4*)&mu[(size_t)n * 64 + c4] = acc;
        mub[(size_t)n * 64 + c4 + 0] = f2b(acc.x);
        mub[(size_t)n * 64 + c4 + 1] = f2b(acc.y);
        mub[(size_t)n * 64 + c4 + 2] = f2b(acc.z);
        mub[(size_t)n * 64 + c4 + 3] = f2b(acc.w);
    } else {
        *(float4*)&lv[(size_t)n * 64 + (c4 - 64)] = acc;
    }
}

// ---------------------------------------------------------------------------
// pred = mu @ mu.T via bf16 MFMA; mub (1.28 MB) is L2-resident.
// Epilogue: LDS-staged coalesced rows + NONTEMPORAL stores (400 MB stream,
// never re-read -> don't let it churn L2). Uses clang ext-vector f32x4
// (HIP float4 class is rejected by __builtin_nontemporal_store).
// ---------------------------------------------------------------------------
__global__ __launch_bounds__(256) void pred_mfma(const unsigned short* __restrict__ mub,
                                                 float* __restrict__ pred) {
    __shared__ float st[4][16][68];
    const int t = threadIdx.x, wid = t >> 6, lane = t & 63;
    const int rb = blockIdx.x * 128 + (wid >> 1) * 64;
    const int cb = blockIdx.y * 128 + (wid & 1) * 64;
    const int fr = lane & 15, fk = (lane >> 4) * 8;
    f32x4 acc[4][4] = {};

    #pragma unroll
    for (int ks = 0; ks < 2; ++ks) {
        bf16x8 af[4], bfv[4];
        #pragma unroll
        for (int m = 0; m < 4; ++m) {
            int r = min(rb + m * 16 + fr, N_NODES - 1);
            af[m] = *(const bf16x8*)&mub[(size_t)r * 64 + ks * 32 + fk];
        }
        #pragma unroll
        for (int n = 0; n < 4; ++n) {
            int c = min(cb + n * 16 + fr, N_NODES - 1);
            bfv[n] = *(const bf16x8*)&mub[(size_t)c * 64 + ks * 32 + fk];
        }
        #pragma unroll
        for (int m = 0; m < 4; ++m)
            #pragma unroll
            for (int n = 0; n < 4; ++n)
                acc[m][n] = __builtin_amdgcn_mfma_f32_16x16x32_bf16(af[m], bfv[n], acc[m][n], 0, 0, 0);
    }

    #pragma unroll
    for (int m = 0; m < 4; ++m) {
        #pragma unroll
        for (int n = 0; n < 4; ++n)
            #pragma unroll
            for (int i = 0; i < 4; ++i)
                st[wid][(lane >> 4) * 4 + i][n * 16 + (lane & 15)] = acc[m][n][i];
        // wave-private region: in-wave lgkmcnt ordering suffices (no barrier)
        int rbase = rb + m * 16;
        #pragma unroll
        for (int it = 0; it < 4; ++it) {
            int row   = it * 4 + (lane >> 4);
            int chunk = lane & 15;
            int grow  = rbase + row;
            int gcol  = cb + chunk * 4;
            if (grow < N_NODES) {
                f32x4 v = *(const f32x4*)&st[wid][row][chunk * 4];
                if (gcol + 3 < N_NODES) {
                    __builtin_nontemporal_store(v, (f32x4*)&pred[(size_t)grow * N_NODES + gcol]);
                } else {
                    #pragma unroll
                    for (int j = 0; j < 4; ++j)
                        if (gcol + j < N_NODES)
                            __builtin_nontemporal_store(v[j], &pred[(size_t)grow * N_NODES + gcol + j]);
                }
            }
        }
    }
}

// ---------------------------------------------------------------------------
extern "C" void kernel_launch(void* const* d_in, const int* in_sizes, int n_in,
                              void* d_out, int out_size, void* d_ws, size_t ws_size,
                              hipStream_t stream) {
    const float* x    = (const float*)d_in[0];
    const int*   esrc = (const int*)d_in[1];
    const int*   edst = (const int*)d_in[2];
    const float* ew   = (const float*)d_in[3];
    const float* W1   = (const float*)d_in[4];
    const float* W2   = (const float*)d_in[5];
    const float* W3   = (const float*)d_in[6];

    float* pred = (float*)d_out;
    float* mu   = pred + (size_t)N_NODES * N_NODES;
    float* lv   = mu   + (size_t)N_NODES * H2;

    char* ws = (char*)d_ws;
    unsigned short* sup1b = (unsigned short*)ws; ws += (size_t)N_NODES * H1 * sizeof(short);
    float* h1       = (float*)ws; ws += (size_t)N_NODES * H1 * sizeof(float);
    float* support2 = (float*)ws; ws += (size_t)N_NODES * 2 * H2 * sizeof(float);
    int*   cnt      = (int*)ws;   ws += (size_t)N_NODES * sizeof(int);
    int*   bsrc     = (int*)ws;   ws += (size_t)N_NODES * CAP * sizeof(int);
    float* bw       = (float*)ws; ws += (size_t)N_NODES * CAP * sizeof(float);
    unsigned short* xb  = (unsigned short*)ws; ws += (size_t)N_NODES * KP * sizeof(short);
    unsigned short* w1t = (unsigned short*)ws; ws += (size_t)H1 * KP * sizeof(short);
    unsigned short* mub = (unsigned short*)ws; ws += (size_t)N_NODES * H2 * sizeof(short);

    (void)hipMemsetAsync(cnt, 0, N_NODES * sizeof(int), stream);
    prep<<<NB_BUCKET + NB_CONVX + NB_CONVW, 256, 0, stream>>>(esrc, edst, ew, x, W1,
                                                              cnt, bsrc, bw, xb, w1t);
    gemm1_mfma<<<640, 256, 0, stream>>>(xb, w1t, sup1b);
    gather_h1<<<N_NODES / 4, 256, 0, stream>>>(sup1b, cnt, bsrc, bw, h1);
    gemm_h1w23<<<N_NODES / 16, 256, 0, stream>>>(h1, W2, W3, support2);
    gather_muvar<<<N_NODES / 8, 256, 0, stream>>>(support2, cnt, bsrc, bw, mu, lv, mub);
    pred_mfma<<<dim3((N_NODES + 127) / 128, (N_NODES + 127) / 128), 256, 0, stream>>>(mub, pred);
}